// Round 1
// baseline (882.806 us; speedup 1.0000x reference)
//
#include <hip/hip_runtime.h>
#include <hip/hip_bf16.h>

typedef __attribute__((ext_vector_type(8))) short short8_t;
typedef __attribute__((ext_vector_type(4))) float f32x4;

#define DEV __device__ __forceinline__

constexpr int BB = 8;           // batch
constexpr int NV = 10242;       // vertices
constexpr int NE = 61440;       // edges
constexpr int MROWS = BB * NV;  // 81936
constexpr int KD = 512;         // K for layers 1-5

DEV float bf2f(ushort u) { union { unsigned i; float f; } v; v.i = ((unsigned)u) << 16; return v.f; }
DEV ushort f2bf(float f) {
    union { unsigned i; float f; } v; v.f = f;
    unsigned b = v.i;
    b += 0x7fffu + ((b >> 16) & 1u);   // RNE
    return (ushort)(b >> 16);
}

// ---------------- CSR build ----------------
__global__ void k_init(int* deg, int* fill) {
    int i = blockIdx.x * 256 + threadIdx.x;
    if (i < NV) { deg[i] = 1; fill[i] = 0; }   // self-loop counts as 1
}

__global__ void k_count(const int* __restrict__ ei, int* __restrict__ deg) {
    int e = blockIdx.x * 256 + threadIdx.x;
    if (e < NE) atomicAdd(&deg[ei[NE + e]], 1);   // dst row of edge_indices
}

__global__ void k_dinv(const int* __restrict__ deg, float* __restrict__ dinv) {
    int i = blockIdx.x * 256 + threadIdx.x;
    if (i < NV) dinv[i] = rsqrtf((float)deg[i]);
}

__global__ __launch_bounds__(1024) void k_scan(const int* __restrict__ cnt, int* __restrict__ rp) {
    __shared__ int part[1024];
    const int t = threadIdx.x;
    const int chunk = (NV + 1023) / 1024;   // 11
    int b0 = t * chunk, b1 = min(b0 + chunk, NV);
    int s = 0;
    for (int i = b0; i < b1; ++i) s += cnt[i];
    part[t] = s;
    __syncthreads();
    for (int off = 1; off < 1024; off <<= 1) {
        int v = (t >= off) ? part[t - off] : 0;
        __syncthreads();
        part[t] += v;
        __syncthreads();
    }
    int run = (t == 0) ? 0 : part[t - 1];
    for (int i = b0; i < b1; ++i) { rp[i] = run; run += cnt[i]; }
    if (t == 1023) rp[NV] = part[1023];
}

__global__ void k_fill(const int* __restrict__ ei, const int* __restrict__ rp,
                       int* __restrict__ fill, const float* __restrict__ dinv,
                       int* __restrict__ ci, float* __restrict__ val) {
    int e = blockIdx.x * 256 + threadIdx.x;
    if (e >= NE + NV) return;
    int s, d;
    if (e < NE) { s = ei[e]; d = ei[NE + e]; }
    else        { s = d = e - NE; }           // self-loops
    int p = atomicAdd(&fill[d], 1);
    int pos = rp[d] + p;
    ci[pos] = s;
    val[pos] = dinv[s] * dinv[d];
}

// ---------------- weight convert / transpose:  Wt[n][k] = bf16(W[k][n]) ----------------
__global__ void k_wconv(const float* __restrict__ W, ushort* __restrict__ Wt, int Kd, int Nc) {
    int idx = blockIdx.x * 256 + threadIdx.x;
    if (idx >= Kd * Nc) return;
    int n = idx / Kd, k = idx - n * Kd;
    Wt[idx] = f2bf(W[(size_t)k * Nc + n]);
}

// ---------------- layer 1 ----------------
// base[b][c] = sum_k img[b][k] * W1[3+k][c]
__global__ __launch_bounds__(128) void k_l1base(const float* __restrict__ img, const float* __restrict__ W1,
                                                float* __restrict__ base) {
    int c = blockIdx.x * 128 + threadIdx.x;   // grid.x = 4
    int b = blockIdx.y;
    float s = 0.f;
    for (int k = 0; k < 512; ++k) s = fmaf(img[b * 512 + k], W1[(size_t)(3 + k) * 512 + c], s);
    base[b * 512 + c] = s;
}

// h[b,n,c] = v0*W1[0][c] + v1*W1[1][c] + v2*W1[2][c] + base[b][c]
__global__ __launch_bounds__(128) void k_l1h(const float* __restrict__ verts, const float* __restrict__ W1,
                                             const float* __restrict__ base, ushort* __restrict__ h) {
    int i = blockIdx.x, b = blockIdx.y;
    size_t row = (size_t)b * NV + i;
    float v0 = verts[row * 3 + 0], v1 = verts[row * 3 + 1], v2 = verts[row * 3 + 2];
    int c = threadIdx.x * 4;
    float4 w0 = *(const float4*)&W1[c];
    float4 w1 = *(const float4*)&W1[512 + c];
    float4 w2 = *(const float4*)&W1[1024 + c];
    float4 bs = *(const float4*)&base[b * 512 + c];
    ushort4 o;
    o.x = f2bf(v0 * w0.x + v1 * w1.x + v2 * w2.x + bs.x);
    o.y = f2bf(v0 * w0.y + v1 * w1.y + v2 * w2.y + bs.y);
    o.z = f2bf(v0 * w0.z + v1 * w1.z + v2 * w2.z + bs.z);
    o.w = f2bf(v0 * w0.w + v1 * w1.w + v2 * w2.w + bs.w);
    *(ushort4*)&h[row * 512 + c] = o;
}

// ---------------- GEMM: C[M,Nc] = A[M,512] @ Wt[Nc,512]^T  (bf16 in, bf16 out, f32 acc) ----------------
__global__ __launch_bounds__(256) void k_gemm(const ushort* __restrict__ A, const ushort* __restrict__ Bt,
                                              ushort* __restrict__ C, int Mr, int Nc) {
    __shared__ __align__(16) ushort lA[2][4096];   // [128 rows][32 k]
    __shared__ __align__(16) ushort lB[2][4096];   // [128 cols][32 k]
    const int t = threadIdx.x;
    const int lane = t & 63, w = t >> 6;
    const int wr = w >> 1, wc = w & 1;
    const int r0 = blockIdx.x * 128, c0 = blockIdx.y * 128;

    const ushort* gA[2]; const ushort* gB[2];
    int ldsoff[2];
    #pragma unroll
    for (int i2 = 0; i2 < 2; ++i2) {
        int idx = i2 * 256 + t;
        int row = idx >> 2, slot = idx & 3;
        int ar = min(r0 + row, Mr - 1);
        int bc = min(c0 + row, Nc - 1);
        gA[i2] = A + (size_t)ar * KD + slot * 8;
        gB[i2] = Bt + (size_t)bc * KD + slot * 8;
        ldsoff[i2] = i2 * 2048 + w * 512;   // elements; wave-uniform
    }

    auto stage = [&](int buf, int kt) {
        int ko = kt * 32;
        #pragma unroll
        for (int i2 = 0; i2 < 2; ++i2) {
            __builtin_amdgcn_global_load_lds(
                (const __attribute__((address_space(1))) void*)(gA[i2] + ko),
                (__attribute__((address_space(3))) void*)(&lA[buf][ldsoff[i2]]), 16, 0, 0);
            __builtin_amdgcn_global_load_lds(
                (const __attribute__((address_space(1))) void*)(gB[i2] + ko),
                (__attribute__((address_space(3))) void*)(&lB[buf][ldsoff[i2]]), 16, 0, 0);
        }
    };

    f32x4 acc[4][4] = {};
    stage(0, 0);
    __syncthreads();
    int cur = 0;
    const int kslot = (lane >> 4) * 8;
    const int rloc = lane & 15;
    for (int kt = 0; kt < 16; ++kt) {
        if (kt < 15) stage(cur ^ 1, kt + 1);
        short8_t af[4], bfr[4];
        #pragma unroll
        for (int m = 0; m < 4; ++m) {
            af[m]  = *(const short8_t*)&lA[cur][(wr * 64 + m * 16 + rloc) * 32 + kslot];
            bfr[m] = *(const short8_t*)&lB[cur][(wc * 64 + m * 16 + rloc) * 32 + kslot];
        }
        #pragma unroll
        for (int m = 0; m < 4; ++m)
            #pragma unroll
            for (int n = 0; n < 4; ++n)
                acc[m][n] = __builtin_amdgcn_mfma_f32_16x16x32_bf16(af[m], bfr[n], acc[m][n], 0, 0, 0);
        __syncthreads();
        cur ^= 1;
    }

    // epilogue: C row = (lane>>4)*4 + r, col = lane&15  (verified m89 layout)
    const int orow = r0 + wr * 64 + (lane >> 4) * 4;
    const int ocol = c0 + wc * 64 + rloc;
    #pragma unroll
    for (int m = 0; m < 4; ++m) {
        #pragma unroll
        for (int n = 0; n < 4; ++n) {
            int gc = ocol + n * 16;
            if (gc >= Nc) continue;
            #pragma unroll
            for (int r = 0; r < 4; ++r) {
                int gr = orow + m * 16 + r;
                if (gr < Mr) C[(size_t)gr * Nc + gc] = f2bf(acc[m][n][r]);
            }
        }
    }
}

// ---------------- aggregation (CSR gather), bias + optional relu fused ----------------
template <int F, bool RELU>
__global__ __launch_bounds__(128) void k_agg(const ushort* __restrict__ h, ushort* __restrict__ xo,
                                             const int* __restrict__ rp, const int* __restrict__ ci,
                                             const float* __restrict__ val, const float* __restrict__ bias) {
    constexpr int TPR = F / 4;          // threads per row
    constexpr int RPB = 128 / TPR;      // rows per block
    const int t = threadIdx.x;
    const int i = blockIdx.x * RPB + t / TPR;
    const int b = blockIdx.y;
    if (i >= NV) return;
    const int fo = (t % TPR) * 4;
    const int r0 = rp[i], r1 = rp[i + 1];
    const ushort* hb = h + (size_t)b * NV * F;
    float a0 = 0, a1 = 0, a2 = 0, a3 = 0;
    for (int e = r0; e < r1; ++e) {
        int j = ci[e];
        float wv = val[e];
        ushort4 v = *(const ushort4*)&hb[(size_t)j * F + fo];
        a0 = fmaf(wv, bf2f(v.x), a0);
        a1 = fmaf(wv, bf2f(v.y), a1);
        a2 = fmaf(wv, bf2f(v.z), a2);
        a3 = fmaf(wv, bf2f(v.w), a3);
    }
    a0 += bias[fo + 0]; a1 += bias[fo + 1]; a2 += bias[fo + 2]; a3 += bias[fo + 3];
    if (RELU) { a0 = fmaxf(a0, 0.f); a1 = fmaxf(a1, 0.f); a2 = fmaxf(a2, 0.f); a3 = fmaxf(a3, 0.f); }
    ushort4 o; o.x = f2bf(a0); o.y = f2bf(a1); o.z = f2bf(a2); o.w = f2bf(a3);
    *(ushort4*)&xo[((size_t)b * NV + i) * F + fo] = o;
}

// ---------------- layer 6: h3 = x64 @ W6 (64x3, f32) ----------------
__global__ __launch_bounds__(256) void k_l6(const ushort* __restrict__ x64, const float* __restrict__ W6,
                                            float* __restrict__ h3) {
    __shared__ float w[192];
    if (threadIdx.x < 192) w[threadIdx.x] = W6[threadIdx.x];
    __syncthreads();
    int r = blockIdx.x * 256 + threadIdx.x;
    if (r >= MROWS) return;
    const ushort* xr = x64 + (size_t)r * 64;
    float a0 = 0, a1 = 0, a2 = 0;
    #pragma unroll 8
    for (int k = 0; k < 64; ++k) {
        float xv = bf2f(xr[k]);
        a0 = fmaf(xv, w[k * 3 + 0], a0);
        a1 = fmaf(xv, w[k * 3 + 1], a1);
        a2 = fmaf(xv, w[k * 3 + 2], a2);
    }
    float* o = h3 + (size_t)r * 3;
    o[0] = a0; o[1] = a1; o[2] = a2;
}

__global__ __launch_bounds__(256) void k_agg3(const float* __restrict__ h3, float* __restrict__ out,
                                              const int* __restrict__ rp, const int* __restrict__ ci,
                                              const float* __restrict__ val, const float* __restrict__ b6) {
    int idx = blockIdx.x * 256 + threadIdx.x;
    if (idx >= MROWS) return;
    int b = idx / NV, i = idx - b * NV;
    float a0 = b6[0], a1 = b6[1], a2 = b6[2];
    int r0 = rp[i], r1 = rp[i + 1];
    const float* hb = h3 + (size_t)b * NV * 3;
    for (int e = r0; e < r1; ++e) {
        int j = ci[e];
        float wv = val[e];
        const float* hr = hb + (size_t)j * 3;
        a0 = fmaf(wv, hr[0], a0);
        a1 = fmaf(wv, hr[1], a1);
        a2 = fmaf(wv, hr[2], a2);
    }
    float* o = out + (size_t)idx * 3;
    o[0] = a0; o[1] = a1; o[2] = a2;
}

// ---------------- launcher ----------------
extern "C" void kernel_launch(void* const* d_in, const int* in_sizes, int n_in,
                              void* d_out, int out_size, void* d_ws, size_t ws_size,
                              hipStream_t stream) {
    const float* verts = (const float*)d_in[0];
    const float* img   = (const float*)d_in[1];
    const int*   ei    = (const int*)d_in[2];
    const float* W1 = (const float*)d_in[3];  const float* b1 = (const float*)d_in[4];
    const float* W2 = (const float*)d_in[5];  const float* b2 = (const float*)d_in[6];
    const float* W3 = (const float*)d_in[7];  const float* b3 = (const float*)d_in[8];
    const float* W4 = (const float*)d_in[9];  const float* b4 = (const float*)d_in[10];
    const float* W5 = (const float*)d_in[11]; const float* b5 = (const float*)d_in[12];
    const float* W6 = (const float*)d_in[13]; const float* b6 = (const float*)d_in[14];
    float* out = (float*)d_out;

    char* ws = (char*)d_ws;
    size_t off = 0;
    auto carve = [&](size_t bytes) -> void* {
        void* q = ws + off;
        off += (bytes + 255) & ~(size_t)255;
        return q;
    };
    ushort* bufX = (ushort*)carve((size_t)MROWS * 512 * 2);   // activations (GEMM input)
    ushort* bufH = (ushort*)carve((size_t)MROWS * 512 * 2);   // pre-aggregation h
    ushort* Wt2  = (ushort*)carve((size_t)512 * 512 * 2);
    ushort* Wt3  = (ushort*)carve((size_t)512 * 512 * 2);
    ushort* Wt4  = (ushort*)carve((size_t)512 * 512 * 2);
    ushort* Wt5  = (ushort*)carve((size_t)64 * 512 * 2);
    float*  basev = (float*)carve((size_t)BB * 512 * 4);
    int*    deg  = (int*)carve((size_t)NV * 4);
    int*    fill = (int*)carve((size_t)NV * 4);
    float*  dinv = (float*)carve((size_t)NV * 4);
    int*    rp   = (int*)carve((size_t)(NV + 1) * 4);
    int*    ci   = (int*)carve((size_t)(NE + NV) * 4);
    float*  valv = (float*)carve((size_t)(NE + NV) * 4);
    float*  h3   = (float*)carve((size_t)MROWS * 3 * 4);

    dim3 b256(256);
    // CSR build
    k_init<<<dim3((NV + 255) / 256), b256, 0, stream>>>(deg, fill);
    k_count<<<dim3((NE + 255) / 256), b256, 0, stream>>>(ei, deg);
    k_dinv<<<dim3((NV + 255) / 256), b256, 0, stream>>>(deg, dinv);
    k_scan<<<dim3(1), dim3(1024), 0, stream>>>(deg, rp);
    k_fill<<<dim3((NE + NV + 255) / 256), b256, 0, stream>>>(ei, rp, fill, dinv, ci, valv);
    // weights -> bf16 transposed
    k_wconv<<<dim3((512 * 512 + 255) / 256), b256, 0, stream>>>(W2, Wt2, 512, 512);
    k_wconv<<<dim3((512 * 512 + 255) / 256), b256, 0, stream>>>(W3, Wt3, 512, 512);
    k_wconv<<<dim3((512 * 512 + 255) / 256), b256, 0, stream>>>(W4, Wt4, 512, 512);
    k_wconv<<<dim3((512 * 64 + 255) / 256), b256, 0, stream>>>(W5, Wt5, 512, 64);
    // layer 1 (broadcast trick)
    k_l1base<<<dim3(4, BB), dim3(128), 0, stream>>>(img, W1, basev);
    k_l1h<<<dim3(NV, BB), dim3(128), 0, stream>>>(verts, W1, basev, bufH);
    k_agg<512, false><<<dim3(NV, BB), dim3(128), 0, stream>>>(bufH, bufX, rp, ci, valv, b1);
    // layer 2 (+relu)
    k_gemm<<<dim3(641, 4), b256, 0, stream>>>(bufX, Wt2, bufH, MROWS, 512);
    k_agg<512, true><<<dim3(NV, BB), dim3(128), 0, stream>>>(bufH, bufX, rp, ci, valv, b2);
    // layer 3
    k_gemm<<<dim3(641, 4), b256, 0, stream>>>(bufX, Wt3, bufH, MROWS, 512);
    k_agg<512, false><<<dim3(NV, BB), dim3(128), 0, stream>>>(bufH, bufX, rp, ci, valv, b3);
    // layer 4 (+relu)
    k_gemm<<<dim3(641, 4), b256, 0, stream>>>(bufX, Wt4, bufH, MROWS, 512);
    k_agg<512, true><<<dim3(NV, BB), dim3(128), 0, stream>>>(bufH, bufX, rp, ci, valv, b4);
    // layer 5 (512 -> 64)
    k_gemm<<<dim3(641, 1), b256, 0, stream>>>(bufX, Wt5, bufH, MROWS, 64);
    k_agg<64, false><<<dim3((NV + 7) / 8, BB), dim3(128), 0, stream>>>(bufH, bufX, rp, ci, valv, b5);
    // layer 6 (64 -> 3, f32) + final aggregation into d_out
    k_l6<<<dim3((MROWS + 255) / 256), b256, 0, stream>>>(bufX, W6, h3);
    k_agg3<<<dim3((MROWS + 255) / 256), b256, 0, stream>>>(h3, out, rp, ci, valv, b6);
}

// Round 2
// 740.777 us; speedup vs baseline: 1.1917x; 1.1917x over previous
//
#include <hip/hip_runtime.h>
#include <hip/hip_bf16.h>

typedef __attribute__((ext_vector_type(8))) short short8_t;
typedef __attribute__((ext_vector_type(4))) float f32x4;

#define DEV __device__ __forceinline__

constexpr int BB = 8;           // batch
constexpr int NV = 10242;       // vertices
constexpr int NE = 61440;       // edges
constexpr int MROWS = BB * NV;  // 81936
constexpr int KD = 512;         // K for layers 1-5

DEV float bf2f(ushort u) { union { unsigned i; float f; } v; v.i = ((unsigned)u) << 16; return v.f; }
DEV ushort f2bf(float f) {
    union { unsigned i; float f; } v; v.f = f;
    unsigned b = v.i;
    b += 0x7fffu + ((b >> 16) & 1u);   // RNE
    return (ushort)(b >> 16);
}

// ---------------- CSR build ----------------
__global__ void k_init(int* deg, int* fill) {
    int i = blockIdx.x * 256 + threadIdx.x;
    if (i < NV) { deg[i] = 1; fill[i] = 0; }   // self-loop counts as 1
}

__global__ void k_count(const int* __restrict__ ei, int* __restrict__ deg) {
    int e = blockIdx.x * 256 + threadIdx.x;
    if (e < NE) atomicAdd(&deg[ei[NE + e]], 1);   // dst row of edge_indices
}

__global__ void k_dinv(const int* __restrict__ deg, float* __restrict__ dinv) {
    int i = blockIdx.x * 256 + threadIdx.x;
    if (i < NV) dinv[i] = rsqrtf((float)deg[i]);
}

__global__ __launch_bounds__(1024) void k_scan(const int* __restrict__ cnt, int* __restrict__ rp) {
    __shared__ int part[1024];
    const int t = threadIdx.x;
    const int chunk = (NV + 1023) / 1024;   // 11
    int b0 = t * chunk, b1 = min(b0 + chunk, NV);
    int s = 0;
    for (int i = b0; i < b1; ++i) s += cnt[i];
    part[t] = s;
    __syncthreads();
    for (int off = 1; off < 1024; off <<= 1) {
        int v = (t >= off) ? part[t - off] : 0;
        __syncthreads();
        part[t] += v;
        __syncthreads();
    }
    int run = (t == 0) ? 0 : part[t - 1];
    for (int i = b0; i < b1; ++i) { rp[i] = run; run += cnt[i]; }
    if (t == 1023) rp[NV] = part[1023];
}

__global__ void k_fill(const int* __restrict__ ei, const int* __restrict__ rp,
                       int* __restrict__ fill, const float* __restrict__ dinv,
                       int* __restrict__ ci, float* __restrict__ val) {
    int e = blockIdx.x * 256 + threadIdx.x;
    if (e >= NE + NV) return;
    int s, d;
    if (e < NE) { s = ei[e]; d = ei[NE + e]; }
    else        { s = d = e - NE; }           // self-loops
    int p = atomicAdd(&fill[d], 1);
    int pos = rp[d] + p;
    ci[pos] = s;
    val[pos] = dinv[s] * dinv[d];
}

// ---------------- weight convert / transpose:  Wt[n][k] = bf16(W[k][n]) ----------------
__global__ void k_wconv(const float* __restrict__ W, ushort* __restrict__ Wt, int Kd, int Nc) {
    int idx = blockIdx.x * 256 + threadIdx.x;
    if (idx >= Kd * Nc) return;
    int n = idx / Kd, k = idx - n * Kd;
    Wt[idx] = f2bf(W[(size_t)k * Nc + n]);
}

// ---------------- layer 1 ----------------
// base[b][c] = sum_k img[b][k] * W1[3+k][c]
__global__ __launch_bounds__(128) void k_l1base(const float* __restrict__ img, const float* __restrict__ W1,
                                                float* __restrict__ base) {
    int c = blockIdx.x * 128 + threadIdx.x;   // grid.x = 4
    int b = blockIdx.y;
    float s = 0.f;
    for (int k = 0; k < 512; ++k) s = fmaf(img[b * 512 + k], W1[(size_t)(3 + k) * 512 + c], s);
    base[b * 512 + c] = s;
}

// h[row(i,b), c], vertex-major: row = i*BB + b
__global__ __launch_bounds__(128) void k_l1h(const float* __restrict__ verts, const float* __restrict__ W1,
                                             const float* __restrict__ base, ushort* __restrict__ h) {
    int i = blockIdx.x, b = blockIdx.y;
    size_t vrow = (size_t)b * NV + i;          // input order [B][N][3]
    float v0 = verts[vrow * 3 + 0], v1 = verts[vrow * 3 + 1], v2 = verts[vrow * 3 + 2];
    size_t row = (size_t)i * BB + b;           // vertex-major activation row
    int c = threadIdx.x * 4;
    float4 w0 = *(const float4*)&W1[c];
    float4 w1 = *(const float4*)&W1[512 + c];
    float4 w2 = *(const float4*)&W1[1024 + c];
    float4 bs = *(const float4*)&base[b * 512 + c];
    ushort4 o;
    o.x = f2bf(v0 * w0.x + v1 * w1.x + v2 * w2.x + bs.x);
    o.y = f2bf(v0 * w0.y + v1 * w1.y + v2 * w2.y + bs.y);
    o.z = f2bf(v0 * w0.z + v1 * w1.z + v2 * w2.z + bs.z);
    o.w = f2bf(v0 * w0.w + v1 * w1.w + v2 * w2.w + bs.w);
    *(ushort4*)&h[row * 512 + c] = o;
}

// ---------------- GEMM: C[M,Nc] = A[M,512] @ Wt[Nc,512]^T  (bf16 in, bf16 out, f32 acc) ----------------
__global__ __launch_bounds__(256) void k_gemm(const ushort* __restrict__ A, const ushort* __restrict__ Bt,
                                              ushort* __restrict__ C, int Mr, int Nc) {
    __shared__ __align__(16) ushort lA[2][4096];   // [128 rows][32 k]
    __shared__ __align__(16) ushort lB[2][4096];   // [128 cols][32 k]
    const int t = threadIdx.x;
    const int lane = t & 63, w = t >> 6;
    const int wr = w >> 1, wc = w & 1;
    const int r0 = blockIdx.x * 128, c0 = blockIdx.y * 128;

    const ushort* gA[2]; const ushort* gB[2];
    int ldsoff[2];
    #pragma unroll
    for (int i2 = 0; i2 < 2; ++i2) {
        int idx = i2 * 256 + t;
        int row = idx >> 2, slot = idx & 3;
        int ar = min(r0 + row, Mr - 1);
        int bc = min(c0 + row, Nc - 1);
        gA[i2] = A + (size_t)ar * KD + slot * 8;
        gB[i2] = Bt + (size_t)bc * KD + slot * 8;
        ldsoff[i2] = i2 * 2048 + w * 512;   // elements; wave-uniform
    }

    auto stage = [&](int buf, int kt) {
        int ko = kt * 32;
        #pragma unroll
        for (int i2 = 0; i2 < 2; ++i2) {
            __builtin_amdgcn_global_load_lds(
                (const __attribute__((address_space(1))) void*)(gA[i2] + ko),
                (__attribute__((address_space(3))) void*)(&lA[buf][ldsoff[i2]]), 16, 0, 0);
            __builtin_amdgcn_global_load_lds(
                (const __attribute__((address_space(1))) void*)(gB[i2] + ko),
                (__attribute__((address_space(3))) void*)(&lB[buf][ldsoff[i2]]), 16, 0, 0);
        }
    };

    f32x4 acc[4][4] = {};
    stage(0, 0);
    __syncthreads();
    int cur = 0;
    const int kslot = (lane >> 4) * 8;
    const int rloc = lane & 15;
    for (int kt = 0; kt < 16; ++kt) {
        if (kt < 15) stage(cur ^ 1, kt + 1);
        short8_t af[4], bfr[4];
        #pragma unroll
        for (int m = 0; m < 4; ++m) {
            af[m]  = *(const short8_t*)&lA[cur][(wr * 64 + m * 16 + rloc) * 32 + kslot];
            bfr[m] = *(const short8_t*)&lB[cur][(wc * 64 + m * 16 + rloc) * 32 + kslot];
        }
        #pragma unroll
        for (int m = 0; m < 4; ++m)
            #pragma unroll
            for (int n = 0; n < 4; ++n)
                acc[m][n] = __builtin_amdgcn_mfma_f32_16x16x32_bf16(af[m], bfr[n], acc[m][n], 0, 0, 0);
        __syncthreads();
        cur ^= 1;
    }

    const int orow = r0 + wr * 64 + (lane >> 4) * 4;
    const int ocol = c0 + wc * 64 + rloc;
    #pragma unroll
    for (int m = 0; m < 4; ++m) {
        #pragma unroll
        for (int n = 0; n < 4; ++n) {
            int gc = ocol + n * 16;
            if (gc >= Nc) continue;
            #pragma unroll
            for (int r = 0; r < 4; ++r) {
                int gr = orow + m * 16 + r;
                if (gr < Mr) C[(size_t)gr * Nc + gc] = f2bf(acc[m][n][r]);
            }
        }
    }
}

// ---------------- vertex-major batch-fused aggregation ----------------
// One block per vertex i; aggregates ALL 8 batches. Per edge: one contiguous
// chunk of 8 rows * F bf16 (8KB for F=512). Thread t owns 8 consecutive
// elements of the 8*F chunk (16B/lane).
template <int F, int NT, bool RELU>
__global__ __launch_bounds__(NT) void k_aggv(const ushort* __restrict__ h, ushort* __restrict__ xo,
                                             const int* __restrict__ rp, const int* __restrict__ ci,
                                             const float* __restrict__ val, const float* __restrict__ bias) {
    static_assert(NT * 8 == BB * F, "one short8 per thread");
    const int i = blockIdx.x;
    const int t = threadIdx.x;
    const int o0 = t * 8;                 // offset within the 8*F chunk (= b*F + f)
    const int fb = o0 & (F - 1);          // feature index base (multiple of 8)
    const int r0 = rp[i], r1 = rp[i + 1];
    const ushort* hb = h + o0;
    float acc[8] = {};
    int e = r0;
    int j = ci[e];
    float wv = val[e];
    while (true) {
        const short8_t v = *(const short8_t*)(hb + (size_t)j * (BB * F));
        const float w = wv;
        ++e;
        if (e < r1) { j = ci[e]; wv = val[e]; }   // prefetch next edge
        #pragma unroll
        for (int k = 0; k < 8; ++k) acc[k] = fmaf(w, bf2f((ushort)v[k]), acc[k]);
        if (e >= r1) break;
    }
    const float4 bl = *(const float4*)&bias[fb];
    const float4 bh = *(const float4*)&bias[fb + 4];
    const float bb[8] = {bl.x, bl.y, bl.z, bl.w, bh.x, bh.y, bh.z, bh.w};
    short8_t o;
    #pragma unroll
    for (int k = 0; k < 8; ++k) {
        float a = acc[k] + bb[k];
        if (RELU) a = fmaxf(a, 0.f);
        o[k] = (short)f2bf(a);
    }
    *(short8_t*)(xo + (size_t)i * (BB * F) + o0) = o;
}

// ---------------- layer 6: h3 = x64 @ W6 (64x3, f32), rows vertex-major ----------------
__global__ __launch_bounds__(256) void k_l6(const ushort* __restrict__ x64, const float* __restrict__ W6,
                                            float* __restrict__ h3) {
    __shared__ float w[192];
    if (threadIdx.x < 192) w[threadIdx.x] = W6[threadIdx.x];
    __syncthreads();
    int r = blockIdx.x * 256 + threadIdx.x;
    if (r >= MROWS) return;
    const ushort* xr = x64 + (size_t)r * 64;
    float a0 = 0, a1 = 0, a2 = 0;
    #pragma unroll 8
    for (int k = 0; k < 64; ++k) {
        float xv = bf2f(xr[k]);
        a0 = fmaf(xv, w[k * 3 + 0], a0);
        a1 = fmaf(xv, w[k * 3 + 1], a1);
        a2 = fmaf(xv, w[k * 3 + 2], a2);
    }
    float* o = h3 + (size_t)r * 3;
    o[0] = a0; o[1] = a1; o[2] = a2;
}

// final aggregation: h3 vertex-major [i*8+b][3] -> out [b][i][3]
__global__ __launch_bounds__(256) void k_agg3(const float* __restrict__ h3, float* __restrict__ out,
                                              const int* __restrict__ rp, const int* __restrict__ ci,
                                              const float* __restrict__ val, const float* __restrict__ b6) {
    int idx = blockIdx.x * 256 + threadIdx.x;
    if (idx >= MROWS) return;
    int b = idx / NV, i = idx - b * NV;
    float a0 = b6[0], a1 = b6[1], a2 = b6[2];
    int r0 = rp[i], r1 = rp[i + 1];
    for (int e = r0; e < r1; ++e) {
        int j = ci[e];
        float wv = val[e];
        const float* hr = h3 + ((size_t)j * BB + b) * 3;
        a0 = fmaf(wv, hr[0], a0);
        a1 = fmaf(wv, hr[1], a1);
        a2 = fmaf(wv, hr[2], a2);
    }
    float* o = out + (size_t)idx * 3;
    o[0] = a0; o[1] = a1; o[2] = a2;
}

// ---------------- launcher ----------------
extern "C" void kernel_launch(void* const* d_in, const int* in_sizes, int n_in,
                              void* d_out, int out_size, void* d_ws, size_t ws_size,
                              hipStream_t stream) {
    const float* verts = (const float*)d_in[0];
    const float* img   = (const float*)d_in[1];
    const int*   ei    = (const int*)d_in[2];
    const float* W1 = (const float*)d_in[3];  const float* b1 = (const float*)d_in[4];
    const float* W2 = (const float*)d_in[5];  const float* b2 = (const float*)d_in[6];
    const float* W3 = (const float*)d_in[7];  const float* b3 = (const float*)d_in[8];
    const float* W4 = (const float*)d_in[9];  const float* b4 = (const float*)d_in[10];
    const float* W5 = (const float*)d_in[11]; const float* b5 = (const float*)d_in[12];
    const float* W6 = (const float*)d_in[13]; const float* b6 = (const float*)d_in[14];
    float* out = (float*)d_out;

    char* ws = (char*)d_ws;
    size_t off = 0;
    auto carve = [&](size_t bytes) -> void* {
        void* q = ws + off;
        off += (bytes + 255) & ~(size_t)255;
        return q;
    };
    ushort* bufX = (ushort*)carve((size_t)MROWS * 512 * 2);   // activations (GEMM input)
    ushort* bufH = (ushort*)carve((size_t)MROWS * 512 * 2);   // pre-aggregation h
    ushort* Wt2  = (ushort*)carve((size_t)512 * 512 * 2);
    ushort* Wt3  = (ushort*)carve((size_t)512 * 512 * 2);
    ushort* Wt4  = (ushort*)carve((size_t)512 * 512 * 2);
    ushort* Wt5  = (ushort*)carve((size_t)64 * 512 * 2);
    float*  basev = (float*)carve((size_t)BB * 512 * 4);
    int*    deg  = (int*)carve((size_t)NV * 4);
    int*    fill = (int*)carve((size_t)NV * 4);
    float*  dinv = (float*)carve((size_t)NV * 4);
    int*    rp   = (int*)carve((size_t)(NV + 1) * 4);
    int*    ci   = (int*)carve((size_t)(NE + NV) * 4);
    float*  valv = (float*)carve((size_t)(NE + NV) * 4);
    float*  h3   = (float*)carve((size_t)MROWS * 3 * 4);

    dim3 b256(256);
    // CSR build
    k_init<<<dim3((NV + 255) / 256), b256, 0, stream>>>(deg, fill);
    k_count<<<dim3((NE + 255) / 256), b256, 0, stream>>>(ei, deg);
    k_dinv<<<dim3((NV + 255) / 256), b256, 0, stream>>>(deg, dinv);
    k_scan<<<dim3(1), dim3(1024), 0, stream>>>(deg, rp);
    k_fill<<<dim3((NE + NV + 255) / 256), b256, 0, stream>>>(ei, rp, fill, dinv, ci, valv);
    // weights -> bf16 transposed
    k_wconv<<<dim3((512 * 512 + 255) / 256), b256, 0, stream>>>(W2, Wt2, 512, 512);
    k_wconv<<<dim3((512 * 512 + 255) / 256), b256, 0, stream>>>(W3, Wt3, 512, 512);
    k_wconv<<<dim3((512 * 512 + 255) / 256), b256, 0, stream>>>(W4, Wt4, 512, 512);
    k_wconv<<<dim3((512 * 64 + 255) / 256), b256, 0, stream>>>(W5, Wt5, 512, 64);
    // layer 1 (broadcast trick)
    k_l1base<<<dim3(4, BB), dim3(128), 0, stream>>>(img, W1, basev);
    k_l1h<<<dim3(NV, BB), dim3(128), 0, stream>>>(verts, W1, basev, bufH);
    k_aggv<512, 512, false><<<dim3(NV), dim3(512), 0, stream>>>(bufH, bufX, rp, ci, valv, b1);
    // layer 2 (+relu)
    k_gemm<<<dim3(641, 4), b256, 0, stream>>>(bufX, Wt2, bufH, MROWS, 512);
    k_aggv<512, 512, true><<<dim3(NV), dim3(512), 0, stream>>>(bufH, bufX, rp, ci, valv, b2);
    // layer 3
    k_gemm<<<dim3(641, 4), b256, 0, stream>>>(bufX, Wt3, bufH, MROWS, 512);
    k_aggv<512, 512, false><<<dim3(NV), dim3(512), 0, stream>>>(bufH, bufX, rp, ci, valv, b3);
    // layer 4 (+relu)
    k_gemm<<<dim3(641, 4), b256, 0, stream>>>(bufX, Wt4, bufH, MROWS, 512);
    k_aggv<512, 512, true><<<dim3(NV), dim3(512), 0, stream>>>(bufH, bufX, rp, ci, valv, b4);
    // layer 5 (512 -> 64)
    k_gemm<<<dim3(641, 1), b256, 0, stream>>>(bufX, Wt5, bufH, MROWS, 64);
    k_aggv<64, 64, false><<<dim3(NV), dim3(64), 0, stream>>>(bufH, bufX, rp, ci, valv, b5);
    // layer 6 (64 -> 3, f32) + final aggregation into d_out
    k_l6<<<dim3((MROWS + 255) / 256), b256, 0, stream>>>(bufX, W6, h3);
    k_agg3<<<dim3((MROWS + 255) / 256), b256, 0, stream>>>(h3, out, rp, ci, valv, b6);
}

// Round 3
// 717.530 us; speedup vs baseline: 1.2303x; 1.0324x over previous
//
#include <hip/hip_runtime.h>
#include <hip/hip_bf16.h>

typedef __attribute__((ext_vector_type(8))) short short8_t;
typedef __attribute__((ext_vector_type(4))) float f32x4;

#define DEV __device__ __forceinline__

constexpr int BB = 8;           // batch
constexpr int NV = 10242;       // vertices
constexpr int NE = 61440;       // edges
constexpr int MROWS = BB * NV;  // 81936
constexpr int KD = 512;         // K for layers 1-5

DEV float bf2f(ushort u) { union { unsigned i; float f; } v; v.i = ((unsigned)u) << 16; return v.f; }
DEV ushort f2bf(float f) {
    union { unsigned i; float f; } v; v.f = f;
    unsigned b = v.i;
    b += 0x7fffu + ((b >> 16) & 1u);   // RNE
    return (ushort)(b >> 16);
}

// ---------------- CSR build ----------------
__global__ void k_init(int* deg, int* fill) {
    int i = blockIdx.x * 256 + threadIdx.x;
    if (i < NV) { deg[i] = 1; fill[i] = 0; }   // self-loop counts as 1
}

__global__ void k_count(const int* __restrict__ ei, int* __restrict__ deg) {
    int e = blockIdx.x * 256 + threadIdx.x;
    if (e < NE) atomicAdd(&deg[ei[NE + e]], 1);   // dst row of edge_indices
}

__global__ void k_dinv(const int* __restrict__ deg, float* __restrict__ dinv) {
    int i = blockIdx.x * 256 + threadIdx.x;
    if (i < NV) dinv[i] = rsqrtf((float)deg[i]);
}

__global__ __launch_bounds__(1024) void k_scan(const int* __restrict__ cnt, int* __restrict__ rp) {
    __shared__ int part[1024];
    const int t = threadIdx.x;
    const int chunk = (NV + 1023) / 1024;   // 11
    int b0 = t * chunk, b1 = min(b0 + chunk, NV);
    int s = 0;
    for (int i = b0; i < b1; ++i) s += cnt[i];
    part[t] = s;
    __syncthreads();
    for (int off = 1; off < 1024; off <<= 1) {
        int v = (t >= off) ? part[t - off] : 0;
        __syncthreads();
        part[t] += v;
        __syncthreads();
    }
    int run = (t == 0) ? 0 : part[t - 1];
    for (int i = b0; i < b1; ++i) { rp[i] = run; run += cnt[i]; }
    if (t == 1023) rp[NV] = part[1023];
}

__global__ void k_fill(const int* __restrict__ ei, const int* __restrict__ rp,
                       int* __restrict__ fill, const float* __restrict__ dinv,
                       int* __restrict__ ci, float* __restrict__ val) {
    int e = blockIdx.x * 256 + threadIdx.x;
    if (e >= NE + NV) return;
    int s, d;
    if (e < NE) { s = ei[e]; d = ei[NE + e]; }
    else        { s = d = e - NE; }           // self-loops
    int p = atomicAdd(&fill[d], 1);
    int pos = rp[d] + p;
    ci[pos] = s;
    val[pos] = dinv[s] * dinv[d];
}

// ---------------- weight convert / transpose:  Wt[n][k] = bf16(W[k][n]) ----------------
__global__ void k_wconv(const float* __restrict__ W, ushort* __restrict__ Wt, int Kd, int Nc) {
    int idx = blockIdx.x * 256 + threadIdx.x;
    if (idx >= Kd * Nc) return;
    int n = idx / Kd, k = idx - n * Kd;
    Wt[idx] = f2bf(W[(size_t)k * Nc + n]);
}

// ---------------- layer 1 ----------------
// base[b][c] = sum_k img[b][k] * W1[3+k][c]
__global__ __launch_bounds__(128) void k_l1base(const float* __restrict__ img, const float* __restrict__ W1,
                                                float* __restrict__ base) {
    int c = blockIdx.x * 128 + threadIdx.x;   // grid.x = 4
    int b = blockIdx.y;
    float s = 0.f;
    for (int k = 0; k < 512; ++k) s = fmaf(img[b * 512 + k], W1[(size_t)(3 + k) * 512 + c], s);
    base[b * 512 + c] = s;
}

// h[row(i,b), c], vertex-major: row = i*BB + b. 2 rows per 256-thread block.
__global__ __launch_bounds__(256) void k_l1h(const float* __restrict__ verts, const float* __restrict__ W1,
                                             const float* __restrict__ base, ushort* __restrict__ h) {
    const int t = threadIdx.x;
    int row = blockIdx.x * 2 + (t >> 7);       // activation row = i*BB + b
    if (row >= MROWS) return;
    int i = row >> 3, b = row & 7;
    size_t vrow = (size_t)b * NV + i;          // input order [B][N][3]
    float v0 = verts[vrow * 3 + 0], v1 = verts[vrow * 3 + 1], v2 = verts[vrow * 3 + 2];
    int c = (t & 127) * 4;
    float4 w0 = *(const float4*)&W1[c];
    float4 w1 = *(const float4*)&W1[512 + c];
    float4 w2 = *(const float4*)&W1[1024 + c];
    float4 bs = *(const float4*)&base[b * 512 + c];
    ushort4 o;
    o.x = f2bf(v0 * w0.x + v1 * w1.x + v2 * w2.x + bs.x);
    o.y = f2bf(v0 * w0.y + v1 * w1.y + v2 * w2.y + bs.y);
    o.z = f2bf(v0 * w0.z + v1 * w1.z + v2 * w2.z + bs.z);
    o.w = f2bf(v0 * w0.w + v1 * w1.w + v2 * w2.w + bs.w);
    *(ushort4*)&h[(size_t)row * 512 + c] = o;
}

// ---------------- GEMM: C[M,Nc] = A[M,512] @ Wt[Nc,512]^T  (bf16 in, bf16 out, f32 acc) ----------------
// 1-D grid, XCD row-affinity: all column-blocks of a row-chunk land on the same XCD
// (bid%8 round-robin heuristic) so the A-chunk is read from HBM once per XCD.
__global__ __launch_bounds__(256) void k_gemm(const ushort* __restrict__ A, const ushort* __restrict__ Bt,
                                              ushort* __restrict__ C, int Mr, int Nc) {
    const int ncb = (Nc + 127) >> 7;           // column blocks
    const int nrc = (Mr + 127) >> 7;           // row chunks
    const int cpx = (nrc + 7) >> 3;            // row chunks per XCD (ceil)
    const int bid = blockIdx.x;
    const int xcd = bid & 7;
    const int k = bid >> 3;                    // 0 .. cpx*ncb-1
    const int rc = xcd * cpx + k / ncb;
    const int cb = k % ncb;
    if (rc >= nrc) return;

    __shared__ __align__(16) ushort lA[2][4096];   // [128 rows][32 k]
    __shared__ __align__(16) ushort lB[2][4096];   // [128 cols][32 k]
    const int t = threadIdx.x;
    const int lane = t & 63, w = t >> 6;
    const int wr = w >> 1, wc = w & 1;
    const int r0 = rc * 128, c0 = cb * 128;

    const ushort* gA[2]; const ushort* gB[2];
    int ldsoff[2];
    #pragma unroll
    for (int i2 = 0; i2 < 2; ++i2) {
        int idx = i2 * 256 + t;
        int row = idx >> 2, slot = idx & 3;
        int ar = min(r0 + row, Mr - 1);
        int bc = min(c0 + row, Nc - 1);
        gA[i2] = A + (size_t)ar * KD + slot * 8;
        gB[i2] = Bt + (size_t)bc * KD + slot * 8;
        ldsoff[i2] = i2 * 2048 + w * 512;   // elements; wave-uniform
    }

    auto stage = [&](int buf, int kt) {
        int ko = kt * 32;
        #pragma unroll
        for (int i2 = 0; i2 < 2; ++i2) {
            __builtin_amdgcn_global_load_lds(
                (const __attribute__((address_space(1))) void*)(gA[i2] + ko),
                (__attribute__((address_space(3))) void*)(&lA[buf][ldsoff[i2]]), 16, 0, 0);
            __builtin_amdgcn_global_load_lds(
                (const __attribute__((address_space(1))) void*)(gB[i2] + ko),
                (__attribute__((address_space(3))) void*)(&lB[buf][ldsoff[i2]]), 16, 0, 0);
        }
    };

    f32x4 acc[4][4] = {};
    stage(0, 0);
    __syncthreads();
    int cur = 0;
    const int kslot = (lane >> 4) * 8;
    const int rloc = lane & 15;
    for (int kt = 0; kt < 16; ++kt) {
        if (kt < 15) stage(cur ^ 1, kt + 1);
        short8_t af[4], bfr[4];
        #pragma unroll
        for (int m = 0; m < 4; ++m) {
            af[m]  = *(const short8_t*)&lA[cur][(wr * 64 + m * 16 + rloc) * 32 + kslot];
            bfr[m] = *(const short8_t*)&lB[cur][(wc * 64 + m * 16 + rloc) * 32 + kslot];
        }
        #pragma unroll
        for (int m = 0; m < 4; ++m)
            #pragma unroll
            for (int n = 0; n < 4; ++n)
                acc[m][n] = __builtin_amdgcn_mfma_f32_16x16x32_bf16(af[m], bfr[n], acc[m][n], 0, 0, 0);
        __syncthreads();
        cur ^= 1;
    }

    const int orow = r0 + wr * 64 + (lane >> 4) * 4;
    const int ocol = c0 + wc * 64 + rloc;
    #pragma unroll
    for (int m = 0; m < 4; ++m) {
        #pragma unroll
        for (int n = 0; n < 4; ++n) {
            int gc = ocol + n * 16;
            if (gc >= Nc) continue;
            #pragma unroll
            for (int r = 0; r < 4; ++r) {
                int gr = orow + m * 16 + r;
                if (gr < Mr) C[(size_t)gr * Nc + gc] = f2bf(acc[m][n][r]);
            }
        }
    }
}

// ---------------- vertex-major batch-fused aggregation ----------------
// One block per vertex; aggregates all 8 batches. Per edge the block reads one
// contiguous 8*F bf16 chunk. Each thread owns NV8 short8 slices; 2-edge manual
// unroll keeps 2*NV8 independent loads in flight per thread (latency hiding).
template <int F, int NT, bool RELU>
__global__ __launch_bounds__(NT) void k_aggv(const ushort* __restrict__ h, ushort* __restrict__ xo,
                                             const int* __restrict__ rp, const int* __restrict__ ci,
                                             const float* __restrict__ val, const float* __restrict__ bias) {
    constexpr int CH = BB * F;                // chunk elements
    constexpr int NV8 = CH / (8 * NT);        // short8 per thread
    static_assert(NV8 * 8 * NT == CH, "coverage");
    const int i = blockIdx.x;
    const int t = threadIdx.x;
    const int r0 = rp[i], r1 = rp[i + 1];
    float acc[NV8][8] = {};
    int e = r0;
    for (; e + 1 < r1; e += 2) {
        int j0 = ci[e], j1 = ci[e + 1];
        float w0 = val[e], w1 = val[e + 1];
        const ushort* p0 = h + (size_t)j0 * CH + t * 8;
        const ushort* p1 = h + (size_t)j1 * CH + t * 8;
        short8_t v0[NV8], v1[NV8];
        #pragma unroll
        for (int v = 0; v < NV8; ++v) v0[v] = *(const short8_t*)(p0 + v * NT * 8);
        #pragma unroll
        for (int v = 0; v < NV8; ++v) v1[v] = *(const short8_t*)(p1 + v * NT * 8);
        #pragma unroll
        for (int v = 0; v < NV8; ++v)
            #pragma unroll
            for (int k = 0; k < 8; ++k)
                acc[v][k] = fmaf(w1, bf2f((ushort)v1[v][k]),
                             fmaf(w0, bf2f((ushort)v0[v][k]), acc[v][k]));
    }
    if (e < r1) {
        int j0 = ci[e];
        float w0 = val[e];
        const ushort* p0 = h + (size_t)j0 * CH + t * 8;
        short8_t v0[NV8];
        #pragma unroll
        for (int v = 0; v < NV8; ++v) v0[v] = *(const short8_t*)(p0 + v * NT * 8);
        #pragma unroll
        for (int v = 0; v < NV8; ++v)
            #pragma unroll
            for (int k = 0; k < 8; ++k)
                acc[v][k] = fmaf(w0, bf2f((ushort)v0[v][k]), acc[v][k]);
    }
    #pragma unroll
    for (int v = 0; v < NV8; ++v) {
        const int o0 = t * 8 + v * NT * 8;
        const int fb = o0 & (F - 1);
        const float4 bl = *(const float4*)&bias[fb];
        const float4 bh = *(const float4*)&bias[fb + 4];
        const float bb[8] = {bl.x, bl.y, bl.z, bl.w, bh.x, bh.y, bh.z, bh.w};
        short8_t o;
        #pragma unroll
        for (int k = 0; k < 8; ++k) {
            float a = acc[v][k] + bb[k];
            if (RELU) a = fmaxf(a, 0.f);
            o[k] = (short)f2bf(a);
        }
        *(short8_t*)(xo + (size_t)i * CH + o0) = o;
    }
}

// ---------------- layer 6: h3 = x64 @ W6 (64x3, f32), rows vertex-major ----------------
__global__ __launch_bounds__(256) void k_l6(const ushort* __restrict__ x64, const float* __restrict__ W6,
                                            float* __restrict__ h3) {
    __shared__ float w[192];
    if (threadIdx.x < 192) w[threadIdx.x] = W6[threadIdx.x];
    __syncthreads();
    int r = blockIdx.x * 256 + threadIdx.x;
    if (r >= MROWS) return;
    const ushort* xr = x64 + (size_t)r * 64;
    float a0 = 0, a1 = 0, a2 = 0;
    #pragma unroll 8
    for (int k = 0; k < 64; ++k) {
        float xv = bf2f(xr[k]);
        a0 = fmaf(xv, w[k * 3 + 0], a0);
        a1 = fmaf(xv, w[k * 3 + 1], a1);
        a2 = fmaf(xv, w[k * 3 + 2], a2);
    }
    float* o = h3 + (size_t)r * 3;
    o[0] = a0; o[1] = a1; o[2] = a2;
}

// final aggregation: h3 vertex-major [i*8+b][3] -> out [b][i][3]
__global__ __launch_bounds__(256) void k_agg3(const float* __restrict__ h3, float* __restrict__ out,
                                              const int* __restrict__ rp, const int* __restrict__ ci,
                                              const float* __restrict__ val, const float* __restrict__ b6) {
    int idx = blockIdx.x * 256 + threadIdx.x;
    if (idx >= MROWS) return;
    int b = idx / NV, i = idx - b * NV;
    float a0 = b6[0], a1 = b6[1], a2 = b6[2];
    int r0 = rp[i], r1 = rp[i + 1];
    for (int e = r0; e < r1; ++e) {
        int j = ci[e];
        float wv = val[e];
        const float* hr = h3 + ((size_t)j * BB + b) * 3;
        a0 = fmaf(wv, hr[0], a0);
        a1 = fmaf(wv, hr[1], a1);
        a2 = fmaf(wv, hr[2], a2);
    }
    float* o = out + (size_t)idx * 3;
    o[0] = a0; o[1] = a1; o[2] = a2;
}

// ---------------- launcher ----------------
extern "C" void kernel_launch(void* const* d_in, const int* in_sizes, int n_in,
                              void* d_out, int out_size, void* d_ws, size_t ws_size,
                              hipStream_t stream) {
    const float* verts = (const float*)d_in[0];
    const float* img   = (const float*)d_in[1];
    const int*   ei    = (const int*)d_in[2];
    const float* W1 = (const float*)d_in[3];  const float* b1 = (const float*)d_in[4];
    const float* W2 = (const float*)d_in[5];  const float* b2 = (const float*)d_in[6];
    const float* W3 = (const float*)d_in[7];  const float* b3 = (const float*)d_in[8];
    const float* W4 = (const float*)d_in[9];  const float* b4 = (const float*)d_in[10];
    const float* W5 = (const float*)d_in[11]; const float* b5 = (const float*)d_in[12];
    const float* W6 = (const float*)d_in[13]; const float* b6 = (const float*)d_in[14];
    float* out = (float*)d_out;

    char* ws = (char*)d_ws;
    size_t off = 0;
    auto carve = [&](size_t bytes) -> void* {
        void* q = ws + off;
        off += (bytes + 255) & ~(size_t)255;
        return q;
    };
    ushort* bufX = (ushort*)carve((size_t)MROWS * 512 * 2);   // activations (GEMM input)
    ushort* bufH = (ushort*)carve((size_t)MROWS * 512 * 2);   // pre-aggregation h
    ushort* Wt2  = (ushort*)carve((size_t)512 * 512 * 2);
    ushort* Wt3  = (ushort*)carve((size_t)512 * 512 * 2);
    ushort* Wt4  = (ushort*)carve((size_t)512 * 512 * 2);
    ushort* Wt5  = (ushort*)carve((size_t)64 * 512 * 2);
    float*  basev = (float*)carve((size_t)BB * 512 * 4);
    int*    deg  = (int*)carve((size_t)NV * 4);
    int*    fill = (int*)carve((size_t)NV * 4);
    float*  dinv = (float*)carve((size_t)NV * 4);
    int*    rp   = (int*)carve((size_t)(NV + 1) * 4);
    int*    ci   = (int*)carve((size_t)(NE + NV) * 4);
    float*  valv = (float*)carve((size_t)(NE + NV) * 4);
    float*  h3   = (float*)carve((size_t)MROWS * 3 * 4);

    dim3 b256(256);
    // CSR build
    k_init<<<dim3((NV + 255) / 256), b256, 0, stream>>>(deg, fill);
    k_count<<<dim3((NE + 255) / 256), b256, 0, stream>>>(ei, deg);
    k_dinv<<<dim3((NV + 255) / 256), b256, 0, stream>>>(deg, dinv);
    k_scan<<<dim3(1), dim3(1024), 0, stream>>>(deg, rp);
    k_fill<<<dim3((NE + NV + 255) / 256), b256, 0, stream>>>(ei, rp, fill, dinv, ci, valv);
    // weights -> bf16 transposed
    k_wconv<<<dim3((512 * 512 + 255) / 256), b256, 0, stream>>>(W2, Wt2, 512, 512);
    k_wconv<<<dim3((512 * 512 + 255) / 256), b256, 0, stream>>>(W3, Wt3, 512, 512);
    k_wconv<<<dim3((512 * 512 + 255) / 256), b256, 0, stream>>>(W4, Wt4, 512, 512);
    k_wconv<<<dim3((512 * 64 + 255) / 256), b256, 0, stream>>>(W5, Wt5, 512, 64);
    // layer 1 (broadcast trick)
    k_l1base<<<dim3(4, BB), dim3(128), 0, stream>>>(img, W1, basev);
    k_l1h<<<dim3((MROWS + 1) / 2), b256, 0, stream>>>(verts, W1, basev, bufH);
    k_aggv<512, 256, false><<<dim3(NV), dim3(256), 0, stream>>>(bufH, bufX, rp, ci, valv, b1);

    // GEMM grids: 8 XCDs * ceil(nrc/8) row chunks * ncb col blocks
    const int nrc = (MROWS + 127) / 128;            // 641
    const int g512 = 8 * ((nrc + 7) / 8) * 4;       // 2592
    const int g64  = 8 * ((nrc + 7) / 8) * 1;       // 648
    // layer 2 (+relu)
    k_gemm<<<dim3(g512), b256, 0, stream>>>(bufX, Wt2, bufH, MROWS, 512);
    k_aggv<512, 256, true><<<dim3(NV), dim3(256), 0, stream>>>(bufH, bufX, rp, ci, valv, b2);
    // layer 3
    k_gemm<<<dim3(g512), b256, 0, stream>>>(bufX, Wt3, bufH, MROWS, 512);
    k_aggv<512, 256, false><<<dim3(NV), dim3(256), 0, stream>>>(bufH, bufX, rp, ci, valv, b3);
    // layer 4 (+relu)
    k_gemm<<<dim3(g512), b256, 0, stream>>>(bufX, Wt4, bufH, MROWS, 512);
    k_aggv<512, 256, true><<<dim3(NV), dim3(256), 0, stream>>>(bufH, bufX, rp, ci, valv, b4);
    // layer 5 (512 -> 64)
    k_gemm<<<dim3(g64), b256, 0, stream>>>(bufX, Wt5, bufH, MROWS, 64);
    k_aggv<64, 64, false><<<dim3(NV), dim3(64), 0, stream>>>(bufH, bufX, rp, ci, valv, b5);
    // layer 6 (64 -> 3, f32) + final aggregation into d_out
    k_l6<<<dim3((MROWS + 255) / 256), b256, 0, stream>>>(bufX, W6, h3);
    k_agg3<<<dim3((MROWS + 255) / 256), b256, 0, stream>>>(h3, out, rp, ci, valv, b6);
}